// Round 5
// baseline (570.538 us; speedup 1.0000x reference)
//
#include <hip/hip_runtime.h>
#include <hip/hip_bf16.h>

#define O_DIM 8192
#define I_DIM 8192
#define G_DIM 64
#define RANK  128

typedef __bf16 bf16x8 __attribute__((ext_vector_type(8)));
typedef __bf16 bf16x4 __attribute__((ext_vector_type(4)));
typedef float  f32x4  __attribute__((ext_vector_type(4)));
typedef int    i32x4  __attribute__((ext_vector_type(4)));

// ---- pre-pass 1: svd_up [8192 x 128] f32 -> bf16, same layout ----
__global__ void k_convert_up(const float* __restrict__ up, __bf16* __restrict__ A_bf) {
    size_t t = (size_t)blockIdx.x * blockDim.x + threadIdx.x;   // 262144 threads, 4 elems each
    const float4* in4 = (const float4*)up;
    float4 v = in4[t];
    bf16x4 o = { (__bf16)v.x, (__bf16)v.y, (__bf16)v.z, (__bf16)v.w };
    *(bf16x4*)(A_bf + 4 * t) = o;
}

// ---- pre-pass 2: svd_down [128 x 8192] f32 -> Bt [8192 x 128] bf16 (transposed) ----
__global__ void k_transpose_down(const float* __restrict__ down, __bf16* __restrict__ Bt) {
    __shared__ __bf16 tile[64][132];        // +4 pad keeps 8B alignment, breaks bank stride
    int tid = threadIdx.x;
    int ib  = blockIdx.x * 64;              // i-range of this block
    int il  = tid & 63;
    int k4  = tid >> 6;
    for (int kk = 0; kk < 32; ++kk) {
        int k = kk * 4 + k4;
        tile[il][k] = (__bf16)down[(size_t)k * I_DIM + ib + il];   // coalesced 256B reads
    }
    __syncthreads();
    // output region is contiguous: Bt[ib*128 .. (ib+64)*128)
    uint2* dst = (uint2*)(Bt + (size_t)ib * RANK);
    #pragma unroll
    for (int jj = 0; jj < 8; ++jj) {
        int f   = (jj * 256 + tid) * 4;     // element index, multiple of 4
        int i_l = f >> 7;
        int k_l = f & 127;
        dst[jj * 256 + tid] = *(const uint2*)&tile[i_l][k_l];      // coalesced 8B writes
    }
}

// ---- main fused kernel: STREAMING redesign -------------------------------------
// r0/r1/r4 all landed 164-180 us regardless of intra-wave scheduling: short-lived
// 128x128-tile blocks (4096 of them) kept avg in-flight fetch ~4 KB/CU (= the
// observed 2.5 TB/s at ~900 cy latency) and chopped each 32 KB weight row into 64
// time-scattered 512 B slices (DRAM page thrash).
// New shape: block = 16 rows x 8192 cols, grid = 512 = EXACTLY 2 blocks/CU, blocks
// live the whole kernel (zero dispatch churn). Wave = 16 rows x 2048 cols, looping
// over 32 chunks of 64 cols:
//   * A-frags (K=128) loaded ONCE per wave (16 VGPR, stationary)
//   * per chunk: 16 Bt-frag loads (L2-hot) -> weight prefetch for NEXT chunk
//     (wtA/wtB double buffer, static names per rule 20; FIFO: prefetch is newer
//     than this chunk's bfr, so the compiler's counted bfr-wait leaves it in
//     flight through the MFMAs) -> 16 MFMA -> dequant -> NT f32x4 stores
//   * weight/out become 16 sequential per-row streams per wave (8 KB each):
//     DRAM page locality restored; in-flight ~30-60 KB/CU sustained >> 9 KB floor
// Swapped-operand MFMA (verified r4): D row = l15, col = quad*4 + e, so each lane
// owns 4 consecutive out cols -> dwordx4 weight loads + f32x4 stores, no LDS.
// NT stores keep the 268 MB out stream from evicting Bt (2 MB) out of L2.
__global__ __launch_bounds__(256, 2)
void k_main(const int* __restrict__ weight, const float* __restrict__ scale,
            const float* __restrict__ zp, const __bf16* __restrict__ A_bf,
            const __bf16* __restrict__ Bt_bf, float* __restrict__ out) {
    int tid  = threadIdx.x;
    int w    = tid >> 6;
    int lane = tid & 63;
    int l15  = lane & 15;
    int quad = lane >> 4;

    int rowbase = blockIdx.x * 16;          // 512 blocks cover 8192 rows
    int wcb     = w * 2048;                 // wave's column range: [wcb, wcb+2048)
    int row     = rowbase + l15;            // this lane's output row (fixed for life)

    // ---- A-frags, loaded once: A[row][kc*32 + quad*8 + e] ----
    const __bf16* Ap = A_bf + (size_t)row * RANK + quad * 8;
    bf16x8 af[4];
    #pragma unroll
    for (int kc = 0; kc < 4; ++kc)
        af[kc] = *(const bf16x8*)(Ap + kc * 32);

    // lane-base pointers for the streams
    const int*    Wp    = weight + (size_t)row * I_DIM + wcb + quad * 4;
    float*        Op    = out    + (size_t)row * I_DIM + wcb + quad * 4;
    const __bf16* Bbase = Bt_bf  + (size_t)(wcb + l15) * RANK + quad * 8;
    const float*  Sp    = scale  + (size_t)row * G_DIM + (wcb >> 7);
    const float*  Zp    = zp     + (size_t)row * G_DIM + (wcb >> 7);

    // ---- prologue: weight chunk 0 -> wtA ----
    i32x4 wtA[4], wtB[4];
    #pragma unroll
    for (int nb = 0; nb < 4; ++nb)
        wtA[nb] = *(const i32x4*)(Wp + nb * 16);
    __builtin_amdgcn_sched_barrier(0);

    #pragma unroll 1
    for (int gi = 0; gi < 16; ++gi) {       // one scale-group (128 cols) = 2 chunks
        float sv = Sp[gi];
        float zv = Zp[gi];

        // ================= even chunk c = 2*gi: consume wtA, prefetch wtB ======
        {
            int c = 2 * gi;
            const __bf16* Bc = Bbase + (size_t)c * 64 * RANK;
            bf16x8 bfr[4][4];
            #pragma unroll
            for (int nb = 0; nb < 4; ++nb)
                #pragma unroll
                for (int kc = 0; kc < 4; ++kc)
                    bfr[nb][kc] = *(const bf16x8*)(Bc + (size_t)nb * 16 * RANK + kc * 32);
            __builtin_amdgcn_sched_barrier(0);  // bfr+s/z strictly before wt prefetch
            #pragma unroll
            for (int nb = 0; nb < 4; ++nb)      // prefetch chunk c+1 (stays in flight)
                wtB[nb] = *(const i32x4*)(Wp + (c + 1) * 64 + nb * 16);
            __builtin_amdgcn_sched_barrier(0);  // wt issued before the MFMA-side wait

            f32x4 acc[4];
            #pragma unroll
            for (int nb = 0; nb < 4; ++nb) acc[nb] = (f32x4){0.f, 0.f, 0.f, 0.f};
            #pragma unroll
            for (int kc = 0; kc < 4; ++kc)
                #pragma unroll
                for (int nb = 0; nb < 4; ++nb)
                    acc[nb] = __builtin_amdgcn_mfma_f32_16x16x32_bf16(
                        bfr[nb][kc], af[kc], acc[nb], 0, 0, 0);

            #pragma unroll
            for (int nb = 0; nb < 4; ++nb) {    // dequant wtA (drained by bfr-wait)
                f32x4 v;
                #pragma unroll
                for (int e = 0; e < 4; ++e)
                    v[e] = fmaf((float)wtA[nb][e], sv, zv) + acc[nb][e];
                __builtin_nontemporal_store(v, (f32x4*)(Op + c * 64 + nb * 16));
            }
        }

        // ================= odd chunk c = 2*gi+1: consume wtB, prefetch wtA =====
        {
            int c = 2 * gi + 1;
            int pf = (c < 31) ? (c + 1) : 31;   // clamp: last prefetch is a harmless dup
            const __bf16* Bc = Bbase + (size_t)c * 64 * RANK;
            bf16x8 bfr[4][4];
            #pragma unroll
            for (int nb = 0; nb < 4; ++nb)
                #pragma unroll
                for (int kc = 0; kc < 4; ++kc)
                    bfr[nb][kc] = *(const bf16x8*)(Bc + (size_t)nb * 16 * RANK + kc * 32);
            __builtin_amdgcn_sched_barrier(0);
            #pragma unroll
            for (int nb = 0; nb < 4; ++nb)      // prefetch next even chunk
                wtA[nb] = *(const i32x4*)(Wp + pf * 64 + nb * 16);
            __builtin_amdgcn_sched_barrier(0);

            f32x4 acc[4];
            #pragma unroll
            for (int nb = 0; nb < 4; ++nb) acc[nb] = (f32x4){0.f, 0.f, 0.f, 0.f};
            #pragma unroll
            for (int kc = 0; kc < 4; ++kc)
                #pragma unroll
                for (int nb = 0; nb < 4; ++nb)
                    acc[nb] = __builtin_amdgcn_mfma_f32_16x16x32_bf16(
                        bfr[nb][kc], af[kc], acc[nb], 0, 0, 0);

            #pragma unroll
            for (int nb = 0; nb < 4; ++nb) {
                f32x4 v;
                #pragma unroll
                for (int e = 0; e < 4; ++e)
                    v[e] = fmaf((float)wtB[nb][e], sv, zv) + acc[nb][e];
                __builtin_nontemporal_store(v, (f32x4*)(Op + c * 64 + nb * 16));
            }
        }
    }
}

extern "C" void kernel_launch(void* const* d_in, const int* in_sizes, int n_in,
                              void* d_out, int out_size, void* d_ws, size_t ws_size,
                              hipStream_t stream) {
    const int*   weight = (const int*)d_in[0];
    const float* scale  = (const float*)d_in[1];
    const float* zp     = (const float*)d_in[2];
    const float* up     = (const float*)d_in[3];
    const float* down   = (const float*)d_in[4];
    float* out = (float*)d_out;

    __bf16* A_bf  = (__bf16*)d_ws;                  // 8192*128 bf16 = 2 MB
    __bf16* Bt_bf = A_bf + (size_t)O_DIM * RANK;    // 8192*128 bf16 = 2 MB

    k_convert_up<<<1024, 256, 0, stream>>>(up, A_bf);
    k_transpose_down<<<128, 256, 0, stream>>>(down, Bt_bf);

    k_main<<<512, 256, 0, stream>>>(weight, scale, zp, A_bf, Bt_bf, out);
}